// Round 8
// baseline (609.584 us; speedup 1.0000x reference)
//
#include <hip/hip_runtime.h>
#include <hip/hip_bf16.h>
#include <math.h>

#define NVEC 2000
#define DD   768
#define HH   1024
#define KNUM 250
#define MSEL 400
#define MR   399     // m-1 rows
#define OUTW 251
#define PPAD 256                 // padded antecedents per anaphor
#define NPAIR (MR * PPAD)        // 102144 padded pair rows
#define BM 128
#define BN 128
#define BK 64
#define NKT (DD / BK)            // 12
#define NNB (HH / BN)            // 8

typedef short  bf16x8 __attribute__((ext_vector_type(8)));
typedef float  f32x4  __attribute__((ext_vector_type(4)));
typedef unsigned int u32;
typedef u32    u32x4  __attribute__((ext_vector_type(4)));

__device__ __forceinline__ float waveSum(float p) {
#pragma unroll
  for (int off = 32; off >= 1; off >>= 1) p += __shfl_xor(p, off, 64);
  return p;
}
__device__ __forceinline__ float waveMax(float p) {
#pragma unroll
  for (int off = 32; off >= 1; off >>= 1) p = fmaxf(p, __shfl_xor(p, off, 64));
  return p;
}
__device__ __forceinline__ short f2bf(float f) {
  __hip_bfloat16 h = __float2bfloat16(f);     // RNE; pairs fuse to v_cvt_pk_bf16_f32
  return __builtin_bit_cast(short, h);
}
// x[e] = bf16( av[e] * f32(b[e]) )  -- 8-element chunk, in registers
__device__ __forceinline__ bf16x8 prodcvt(const float* av, bf16x8 b) {
  u32x4 u = __builtin_bit_cast(u32x4, b);
  bf16x8 r;
#pragma unroll
  for (int p = 0; p < 4; ++p) {
    const float blo = __builtin_bit_cast(float, u[p] << 16);
    const float bhi = __builtin_bit_cast(float, u[p] & 0xffff0000u);
    r[2 * p]     = f2bf(av[2 * p]     * blo);
    r[2 * p + 1] = f2bf(av[2 * p + 1] * bhi);
  }
  return r;
}

// ---------------- K1: scores = relu(V @ Wm1 + bm1) @ wm2 + bm2 ----------------
__global__ __launch_bounds__(512) void scores_kernel(
    const float* __restrict__ vectors, const float* __restrict__ Wm1,
    const float* __restrict__ bm1, const float* __restrict__ wm2,
    const float* __restrict__ bm2, float* __restrict__ scores) {
  __shared__ float vrow[4 * DD];
  __shared__ float red[8];
  const int tid = threadIdx.x;
  const int base = blockIdx.x * 4;
  for (int idx = tid; idx < 4 * DD; idx += 512)
    vrow[idx] = vectors[base * DD + idx];
  __syncthreads();
  float acc[4][2];
#pragma unroll
  for (int r = 0; r < 4; ++r) { acc[r][0] = 0.f; acc[r][1] = 0.f; }
#pragma unroll 2
  for (int d = 0; d < DD; d += 4) {
    float2 w0 = ((const float2*)(Wm1 + (size_t)(d + 0) * HH))[tid];
    float2 w1 = ((const float2*)(Wm1 + (size_t)(d + 1) * HH))[tid];
    float2 w2 = ((const float2*)(Wm1 + (size_t)(d + 2) * HH))[tid];
    float2 w3 = ((const float2*)(Wm1 + (size_t)(d + 3) * HH))[tid];
#pragma unroll
    for (int r = 0; r < 4; ++r) {
      const float4 a = *(const float4*)(vrow + r * DD + d);
      acc[r][0] += a.x * w0.x; acc[r][1] += a.x * w0.y;
      acc[r][0] += a.y * w1.x; acc[r][1] += a.y * w1.y;
      acc[r][0] += a.z * w2.x; acc[r][1] += a.z * w2.y;
      acc[r][0] += a.w * w3.x; acc[r][1] += a.w * w3.y;
    }
  }
  const float2 b = ((const float2*)bm1)[tid];
  const float2 m = ((const float2*)wm2)[tid];
  const float sc = bm2[0];
  for (int r = 0; r < 4; ++r) {
    float p = fmaxf(acc[r][0] + b.x, 0.f) * m.x + fmaxf(acc[r][1] + b.y, 0.f) * m.y;
    p = waveSum(p);
    if ((tid & 63) == 0) red[tid >> 6] = p;
    __syncthreads();
    if (tid == 0) {
      float t = red[0];
#pragma unroll
      for (int w8 = 1; w8 < 8; ++w8) t += red[w8];
      scores[base + r] = t + sc;
    }
    __syncthreads();
  }
}

// ---------------- K2: bitonic sort (score desc, idx asc) -> top 400 ----------------
__global__ __launch_bounds__(1024) void topsort_kernel(
    const float* __restrict__ scores, int* __restrict__ top) {
  __shared__ float ks[2048];
  __shared__ int   ki[2048];
  const int tid = threadIdx.x;
  for (int e = tid; e < 2048; e += 1024) {
    ks[e] = (e < NVEC) ? scores[e] : -INFINITY;
    ki[e] = e;
  }
  __syncthreads();
  for (int k = 2; k <= 2048; k <<= 1) {
    for (int j = k >> 1; j > 0; j >>= 1) {
      for (int e = tid; e < 2048; e += 1024) {
        const int l = e ^ j;
        if (l > e) {
          const float s1 = ks[e], s2 = ks[l];
          const int i1 = ki[e], i2 = ki[l];
          const bool first = (s1 > s2) || (s1 == s2 && i1 < i2);
          const bool up = ((e & k) == 0);
          if (up ? !first : first) {
            ks[e] = s2; ks[l] = s1; ki[e] = i2; ki[l] = i1;
          }
        }
      }
      __syncthreads();
    }
  }
  if (tid < MSEL) top[tid] = ki[tid];
}

// ---------------- K3: lexsort by (start,end,pos) asc, reversed ----------------
__global__ __launch_bounds__(256) void lexsort_kernel(
    const int* __restrict__ top, const int* __restrict__ sst,
    const int* __restrict__ sen, const float* __restrict__ scores,
    int* __restrict__ perm, float* __restrict__ sfin) {
  __shared__ int s_st[512], s_en[512], s_j[512];
  const int tid = threadIdx.x;
  for (int e = tid; e < 512; e += 256) {
    if (e < MSEL) { const int ti = top[e]; s_st[e] = sst[ti]; s_en[e] = sen[ti]; }
    else { s_st[e] = 0x7fffffff; s_en[e] = 0x7fffffff; }
    s_j[e] = e;
  }
  __syncthreads();
  for (int k = 2; k <= 512; k <<= 1) {
    for (int j = k >> 1; j > 0; j >>= 1) {
      for (int e = tid; e < 512; e += 256) {
        const int l = e ^ j;
        if (l > e) {
          const int a0 = s_st[e], a1 = s_en[e], a2 = s_j[e];
          const int b0 = s_st[l], b1 = s_en[l], b2 = s_j[l];
          const bool first = (a0 < b0) || (a0 == b0 && (a1 < b1 || (a1 == b1 && a2 < b2)));
          const bool up = ((e & k) == 0);
          if (up ? !first : first) {
            s_st[e] = b0; s_en[e] = b1; s_j[e] = b2;
            s_st[l] = a0; s_en[l] = a1; s_j[l] = a2;
          }
        }
      }
      __syncthreads();
    }
  }
  for (int i = tid; i < MSEL; i += 256) {
    const int src = s_j[MSEL - 1 - i];
    const int vi = top[src];
    perm[i] = vi;
    sfin[i] = scores[vi];
  }
}

// ---------------- K4: Ha = v@Wa, Hv = v@Wb; gather Vp (f32) + Vpb (bf16) ----------------
__global__ __launch_bounds__(256) void hab_kernel(
    const float* __restrict__ vectors, const float* __restrict__ Wp1,
    const int* __restrict__ perm, float* __restrict__ Ha, float* __restrict__ Hv,
    float* __restrict__ Vp, ushort* __restrict__ Vpb) {
  __shared__ float vrow[4 * DD];
  const int tid = threadIdx.x;
  const int base = blockIdx.x * 4;
  const int mat = blockIdx.y >> 1;       // 0 = Wa, 1 = Wb
  const int half = blockIdx.y & 1;       // col half
  for (int r = 0; r < 4; ++r) {
    const int pi = perm[base + r];
    for (int d = tid; d < DD; d += 256) {
      const float val = vectors[pi * DD + d];
      vrow[r * DD + d] = val;
      if (blockIdx.y == 0) {
        Vp[(size_t)(base + r) * DD + d] = val;
        Vpb[(size_t)(base + r) * DD + d] = (ushort)f2bf(val);
      }
    }
  }
  __syncthreads();
  float acc[4][2];
#pragma unroll
  for (int r = 0; r < 4; ++r) { acc[r][0] = 0.f; acc[r][1] = 0.f; }
  const float* W = Wp1 + (size_t)mat * DD * HH + half * 512;
#pragma unroll 2
  for (int d = 0; d < DD; d += 4) {
    float2 w0 = ((const float2*)(W + (size_t)(d + 0) * HH))[tid];
    float2 w1 = ((const float2*)(W + (size_t)(d + 1) * HH))[tid];
    float2 w2 = ((const float2*)(W + (size_t)(d + 2) * HH))[tid];
    float2 w3 = ((const float2*)(W + (size_t)(d + 3) * HH))[tid];
#pragma unroll
    for (int r = 0; r < 4; ++r) {
      const float4 a = *(const float4*)(vrow + r * DD + d);
      acc[r][0] += a.x * w0.x; acc[r][1] += a.x * w0.y;
      acc[r][0] += a.y * w1.x; acc[r][1] += a.y * w1.y;
      acc[r][0] += a.z * w2.x; acc[r][1] += a.z * w2.y;
      acc[r][0] += a.w * w3.x; acc[r][1] += a.w * w3.y;
    }
  }
  float* dst = mat ? Hv : Ha;
  for (int r = 0; r < 4; ++r) {
    const int row = base + r;
    if (mat == 0 && row >= MR) continue;
    ((float2*)(dst + (size_t)row * HH + half * 512))[tid] =
        make_float2(acc[r][0], acc[r][1]);
  }
}

// ---------------- K4b: Wt[n][k] = bf16(Wab[k][n]) (transpose + cast, once) ----------------
__global__ __launch_bounds__(256) void wt_kernel(
    const float* __restrict__ Wp1, ushort* __restrict__ Wt) {
  __shared__ float tile[64][65];
  const int kb = blockIdx.x;   // 12 tiles over K=768
  const int nb = blockIdx.y;   // 16 tiles over N=1024
  const float* Wab = Wp1 + 2 * DD * HH;
  for (int idx = threadIdx.x; idx < 64 * 64; idx += 256) {
    const int kk = idx >> 6, nn = idx & 63;
    tile[kk][nn] = Wab[(size_t)(kb * 64 + kk) * HH + nb * 64 + nn];
  }
  __syncthreads();
  for (int idx = threadIdx.x; idx < 64 * 64; idx += 256) {
    const int nn = idx >> 6, kk = idx & 63;
    Wt[(size_t)(nb * 64 + nn) * DD + kb * 64 + kk] = (ushort)f2bf(tile[kk][nn]);
  }
}

// ---------------- K5: pairwise einsum GEMM, minimal-LDS pipeline ----------------
// Block: 128 pair-rows x 128 h-cols, 4 waves 2x2 (wave tile 64x64).
// A: products staged ONCE in LDS (dbuf, XOR-swizzle); sources = Vpb (bf16, cold)
//    x Vp row i (f32, hot) both direct-global. No aL/jrs LDS.
// B: direct global->register from Wt (16B contiguous per lane), kt+1 reg-dbuf.
// LDS ops/kt/block: 16 A ds_writes + 32 af ds_reads = 48  (r6 had ~104).
__global__ __launch_bounds__(256, 2) void pair_kernel(
    const float* __restrict__ Vp, const ushort* __restrict__ Vpb,
    const ushort* __restrict__ Wt,
    const float* __restrict__ bp1, const float* __restrict__ wp2,
    const float* __restrict__ Ha, const float* __restrict__ Hv,
    float* __restrict__ pp) {
  __shared__ __align__(16) ushort As[2][BM * BK];
  __shared__ float redp[BM][2];
  const int tid = threadIdx.x;
  const int mb = blockIdx.x;          // 0..797  (i*2 + khalf)
  const int nb = blockIdx.y;          // 0..7
  const int i = mb >> 1;
  const int khalf = mb & 1;
  const int n0 = nb * BN;
  const int lane = tid & 63;
  const int wid = tid >> 6;
  const int wr = wid >> 1, wc = wid & 1;
  const int lhi = lane >> 4, llo = lane & 15;

  // ---- stage geometry: 4 chunks/thread; cs = tid&7 constant across chunks ----
  const int cs = tid & 7;
  int rowA[4], csx[4];
  const ushort* vsrc[4];
#pragma unroll
  for (int it = 0; it < 4; ++it) {
    const int c = it * 256 + tid;
    rowA[it] = c >> 3;
    csx[it] = cs ^ (rowA[it] & 7);
    int j = i + 1 + khalf * BM + rowA[it];
    if (j > MR) j = MR;
    vsrc[it] = Vpb + (size_t)j * DD + cs * 8;
  }
  const float* avp = Vp + (size_t)i * DD + cs * 8;   // hot row i
  // ---- B fragment pointers (per-lane, 16B contiguous) ----
  const ushort* bptr[4];
#pragma unroll
  for (int ni = 0; ni < 4; ++ni) {
    const int col = n0 + wc * 64 + ni * 16 + llo;
    bptr[ni] = Wt + (size_t)col * DD + lhi * 8;
  }

  f32x4 acc[4][4];
#pragma unroll
  for (int a = 0; a < 4; ++a)
#pragma unroll
    for (int b = 0; b < 4; ++b) acc[a][b] = (f32x4){0.f, 0.f, 0.f, 0.f};

  bf16x8 bc[2][4], bn[2][4];

  // ---- prologue: stage A(0), load B(0) into bc ----
  {
    float av0[8];
    *(float4*)(av0) = *(const float4*)(avp);
    *(float4*)(av0 + 4) = *(const float4*)(avp + 4);
#pragma unroll
    for (int it = 0; it < 4; ++it) {
      const bf16x8 bv = *(const bf16x8*)(vsrc[it]);
      *(bf16x8*)((char*)As[0] + rowA[it] * 128 + (csx[it] << 4)) = prodcvt(av0, bv);
    }
#pragma unroll
    for (int ks = 0; ks < 2; ++ks)
#pragma unroll
      for (int ni = 0; ni < 4; ++ni)
        bc[ks][ni] = *(const bf16x8*)(bptr[ni] + ks * 32);
  }
  __syncthreads();

#define PAIR_ITER(KT, RB, WB, BCUR, BNXT)                                          \
  {                                                                                \
    const int kgn = ((KT) + 1) * BK;                                               \
    bf16x8 bvn[4]; float avn[8];                                                   \
    if ((KT) + 1 < NKT) {                                                          \
      _Pragma("unroll")                                                            \
      for (int ks = 0; ks < 2; ++ks)                                               \
        _Pragma("unroll")                                                          \
        for (int ni = 0; ni < 4; ++ni)                                             \
          BNXT[ks][ni] = *(const bf16x8*)(bptr[ni] + kgn + ks * 32);               \
      _Pragma("unroll")                                                            \
      for (int it = 0; it < 4; ++it) bvn[it] = *(const bf16x8*)(vsrc[it] + kgn);   \
      *(float4*)(avn) = *(const float4*)(avp + kgn);                               \
      *(float4*)(avn + 4) = *(const float4*)(avp + kgn + 4);                       \
    }                                                                              \
    _Pragma("unroll")                                                              \
    for (int ks = 0; ks < 2; ++ks) {                                               \
      bf16x8 af[4];                                                                \
      _Pragma("unroll")                                                            \
      for (int mi = 0; mi < 4; ++mi) {                                             \
        const int row = wr * 64 + mi * 16 + llo;                                   \
        const int ch = (ks * 4 + lhi) ^ (row & 7);                                 \
        af[mi] = *(const bf16x8*)((const char*)(RB) + row * 128 + (ch << 4));      \
      }                                                                            \
      _Pragma("unroll")                                                            \
      for (int mi = 0; mi < 4; ++mi)                                               \
        _Pragma("unroll")                                                          \
        for (int ni = 0; ni < 4; ++ni)                                             \
          acc[mi][ni] = __builtin_amdgcn_mfma_f32_16x16x32_bf16(                   \
              af[mi], BCUR[ks][ni], acc[mi][ni], 0, 0, 0);                         \
    }                                                                              \
    if ((KT) + 1 < NKT) {                                                          \
      _Pragma("unroll")                                                            \
      for (int it = 0; it < 4; ++it)                                               \
        *(bf16x8*)((char*)(WB) + rowA[it] * 128 + (csx[it] << 4)) =                \
            prodcvt(avn, bvn[it]);                                                 \
    }                                                                              \
    __syncthreads();                                                               \
  }

  for (int kt = 0; kt < NKT; kt += 2) {
    PAIR_ITER(kt,     As[0], As[1], bc, bn)
    PAIR_ITER(kt + 1, As[1], As[0], bn, bc)
  }
#undef PAIR_ITER

  // ---- epilogue: relu(acc + Ha_i + Hv_j + bp1) . wp2 over this wave's 64 cols ----
  float hb4[4], wpv[4];
  int cg[4];
#pragma unroll
  for (int ni = 0; ni < 4; ++ni) {
    const int col = n0 + wc * 64 + ni * 16 + llo;
    cg[ni] = col;
    hb4[ni] = Ha[(size_t)i * HH + col] + bp1[col];
    wpv[ni] = wp2[col];
  }
#pragma unroll
  for (int mi = 0; mi < 4; ++mi) {
#pragma unroll
    for (int r = 0; r < 4; ++r) {
      const int rowl = wr * 64 + mi * 16 + lhi * 4 + r;
      int j = i + 1 + khalf * BM + rowl;
      if (j > MR) j = MR;
      float part = 0.f;
#pragma unroll
      for (int ni = 0; ni < 4; ++ni) {
        const float pre = acc[mi][ni][r] + hb4[ni] + Hv[(size_t)j * HH + cg[ni]];
        part += fmaxf(pre, 0.f) * wpv[ni];
      }
      part += __shfl_xor(part, 1, 64);
      part += __shfl_xor(part, 2, 64);
      part += __shfl_xor(part, 4, 64);
      part += __shfl_xor(part, 8, 64);
      if (llo == 0) redp[rowl][wc] = part;   // per-wave column-half partial
    }
  }
  __syncthreads();
  if (tid < BM)
    pp[(size_t)nb * NPAIR + (size_t)mb * BM + tid] = redp[tid][0] + redp[tid][1];
}

// ---------------- K6: sum partials + bias + scores, mask, softmax over 251 ----------------
__global__ __launch_bounds__(256) void softmax_kernel(
    const float* __restrict__ pp, const float* __restrict__ sfin,
    const float* __restrict__ bp2, float* __restrict__ out) {
  __shared__ float red[4];
  const int i = blockIdx.x, tid = threadIdx.x;
  float v;
  if (tid < KNUM) {
    const int jidx = i + 1 + tid;
    const bool valid = jidx < MSEL;
    const int jc = valid ? jidx : MR;
    float s = 0.f;
#pragma unroll
    for (int b = 0; b < NNB; ++b) s += pp[(size_t)b * NPAIR + i * PPAD + tid];
    v = valid ? (s + bp2[0] + sfin[jc] + sfin[i]) : -INFINITY;
  } else if (tid == KNUM) v = 0.f;
  else v = -INFINITY;
  float mx = waveMax(v);
  if ((tid & 63) == 0) red[tid >> 6] = mx;
  __syncthreads();
  const float m = fmaxf(fmaxf(red[0], red[1]), fmaxf(red[2], red[3]));
  __syncthreads();
  const float e = (tid <= KNUM) ? expf(v - m) : 0.f;
  float s = waveSum(e);
  if ((tid & 63) == 0) red[tid >> 6] = s;
  __syncthreads();
  const float tot = red[0] + red[1] + red[2] + red[3];
  if (tid <= KNUM) out[i * OUTW + tid] = e / tot;
}

extern "C" void kernel_launch(void* const* d_in, const int* in_sizes, int n_in,
                              void* d_out, int out_size, void* d_ws, size_t ws_size,
                              hipStream_t stream) {
  const float* vectors = (const float*)d_in[0];
  const float* Wm1 = (const float*)d_in[1];
  const float* bm1 = (const float*)d_in[2];
  const float* wm2 = (const float*)d_in[3];
  const float* bm2 = (const float*)d_in[4];
  const float* Wp1 = (const float*)d_in[5];
  const float* bp1 = (const float*)d_in[6];
  const float* wp2 = (const float*)d_in[7];
  const float* bp2 = (const float*)d_in[8];
  const int* sst = (const int*)d_in[9];
  const int* sen = (const int*)d_in[10];
  float* out = (float*)d_out;
  char* ws = (char*)d_ws;

  float* scores = (float*)(ws);                          // 2000 f32
  int*   top    = (int*)(ws + 8192);                     // 400 i32
  int*   perm   = (int*)(ws + 10240);                    // 400 i32
  float* sfin   = (float*)(ws + 12288);                  // 400 f32
  float* Ha     = (float*)(ws + 16384);                  // 400*1024 f32
  float* Hv     = (float*)(ws + 16384 + 1638400);        // 400*1024 f32
  float* Vp     = (float*)(ws + 3293184);                // 400*768 f32
  ushort* Wt    = (ushort*)(ws + 4521984);               // 1024*768 bf16
  ushort* Vpb   = (ushort*)(ws + 6094848);               // 400*768 bf16
  float* pp     = (float*)(ws + 6709248);                // 8 * 102144 f32 partials

  scores_kernel<<<NVEC / 4, 512, 0, stream>>>(vectors, Wm1, bm1, wm2, bm2, scores);
  topsort_kernel<<<1, 1024, 0, stream>>>(scores, top);
  lexsort_kernel<<<1, 256, 0, stream>>>(top, sst, sen, scores, perm, sfin);
  wt_kernel<<<dim3(12, 16), 256, 0, stream>>>(Wp1, Wt);
  hab_kernel<<<dim3(MSEL / 4, 4), 256, 0, stream>>>(vectors, Wp1, perm, Ha, Hv, Vp, Vpb);
  pair_kernel<<<dim3(MR * 2, NNB), 256, 0, stream>>>(Vp, Vpb, Wt, bp1, wp2, Ha, Hv, pp);
  softmax_kernel<<<MR, 256, 0, stream>>>(pp, sfin, bp2, out);
}

// Round 9
// 440.965 us; speedup vs baseline: 1.3824x; 1.3824x over previous
//
#include <hip/hip_runtime.h>
#include <hip/hip_bf16.h>
#include <math.h>

#define NVEC 2000
#define DD   768
#define HH   1024
#define KNUM 250
#define MSEL 400
#define MR   399     // m-1 rows
#define OUTW 251
#define PPAD 256                 // padded antecedents per anaphor
#define NPAIR (MR * PPAD)        // 102144 padded pair rows
#define BM 256
#define BN 256
#define BK 64
#define NKT (DD / BK)            // 12
#define NNB (HH / BN)            // 4

typedef short  bf16x8 __attribute__((ext_vector_type(8)));
typedef float  f32x4  __attribute__((ext_vector_type(4)));
typedef unsigned int u32;
typedef u32    u32x4  __attribute__((ext_vector_type(4)));

__device__ __forceinline__ float waveSum(float p) {
#pragma unroll
  for (int off = 32; off >= 1; off >>= 1) p += __shfl_xor(p, off, 64);
  return p;
}
__device__ __forceinline__ float waveMax(float p) {
#pragma unroll
  for (int off = 32; off >= 1; off >>= 1) p = fmaxf(p, __shfl_xor(p, off, 64));
  return p;
}
__device__ __forceinline__ short f2bf(float f) {
  __hip_bfloat16 h = __float2bfloat16(f);     // RNE; pairs fuse to v_cvt_pk_bf16_f32
  return __builtin_bit_cast(short, h);
}
__device__ __forceinline__ void gload_lds16(const void* g, void* l) {
  __builtin_amdgcn_global_load_lds(
      (const __attribute__((address_space(1))) u32*)g,
      (__attribute__((address_space(3))) u32*)l, 16, 0, 0);
}
// x[e] = bf16( av[e] * f32(b[e]) )  -- 8-element chunk, in registers
__device__ __forceinline__ bf16x8 prodcvt(const float* av, bf16x8 b) {
  u32x4 u = __builtin_bit_cast(u32x4, b);
  bf16x8 r;
#pragma unroll
  for (int p = 0; p < 4; ++p) {
    const float blo = __builtin_bit_cast(float, u[p] << 16);
    const float bhi = __builtin_bit_cast(float, u[p] & 0xffff0000u);
    r[2 * p]     = f2bf(av[2 * p]     * blo);
    r[2 * p + 1] = f2bf(av[2 * p + 1] * bhi);
  }
  return r;
}

// ---------------- K1: scores = relu(V @ Wm1 + bm1) @ wm2 + bm2 ----------------
__global__ __launch_bounds__(512) void scores_kernel(
    const float* __restrict__ vectors, const float* __restrict__ Wm1,
    const float* __restrict__ bm1, const float* __restrict__ wm2,
    const float* __restrict__ bm2, float* __restrict__ scores) {
  __shared__ float vrow[4 * DD];
  __shared__ float red[8];
  const int tid = threadIdx.x;
  const int base = blockIdx.x * 4;
  for (int idx = tid; idx < 4 * DD; idx += 512)
    vrow[idx] = vectors[base * DD + idx];
  __syncthreads();
  float acc[4][2];
#pragma unroll
  for (int r = 0; r < 4; ++r) { acc[r][0] = 0.f; acc[r][1] = 0.f; }
#pragma unroll 2
  for (int d = 0; d < DD; d += 4) {
    float2 w0 = ((const float2*)(Wm1 + (size_t)(d + 0) * HH))[tid];
    float2 w1 = ((const float2*)(Wm1 + (size_t)(d + 1) * HH))[tid];
    float2 w2 = ((const float2*)(Wm1 + (size_t)(d + 2) * HH))[tid];
    float2 w3 = ((const float2*)(Wm1 + (size_t)(d + 3) * HH))[tid];
#pragma unroll
    for (int r = 0; r < 4; ++r) {
      const float4 a = *(const float4*)(vrow + r * DD + d);
      acc[r][0] += a.x * w0.x; acc[r][1] += a.x * w0.y;
      acc[r][0] += a.y * w1.x; acc[r][1] += a.y * w1.y;
      acc[r][0] += a.z * w2.x; acc[r][1] += a.z * w2.y;
      acc[r][0] += a.w * w3.x; acc[r][1] += a.w * w3.y;
    }
  }
  const float2 b = ((const float2*)bm1)[tid];
  const float2 m = ((const float2*)wm2)[tid];
  const float sc = bm2[0];
  for (int r = 0; r < 4; ++r) {
    float p = fmaxf(acc[r][0] + b.x, 0.f) * m.x + fmaxf(acc[r][1] + b.y, 0.f) * m.y;
    p = waveSum(p);
    if ((tid & 63) == 0) red[tid >> 6] = p;
    __syncthreads();
    if (tid == 0) {
      float t = red[0];
#pragma unroll
      for (int w8 = 1; w8 < 8; ++w8) t += red[w8];
      scores[base + r] = t + sc;
    }
    __syncthreads();
  }
}

// ---------------- K2: bitonic sort (score desc, idx asc) -> top 400 ----------------
__global__ __launch_bounds__(1024) void topsort_kernel(
    const float* __restrict__ scores, int* __restrict__ top) {
  __shared__ float ks[2048];
  __shared__ int   ki[2048];
  const int tid = threadIdx.x;
  for (int e = tid; e < 2048; e += 1024) {
    ks[e] = (e < NVEC) ? scores[e] : -INFINITY;
    ki[e] = e;
  }
  __syncthreads();
  for (int k = 2; k <= 2048; k <<= 1) {
    for (int j = k >> 1; j > 0; j >>= 1) {
      for (int e = tid; e < 2048; e += 1024) {
        const int l = e ^ j;
        if (l > e) {
          const float s1 = ks[e], s2 = ks[l];
          const int i1 = ki[e], i2 = ki[l];
          const bool first = (s1 > s2) || (s1 == s2 && i1 < i2);
          const bool up = ((e & k) == 0);
          if (up ? !first : first) {
            ks[e] = s2; ks[l] = s1; ki[e] = i2; ki[l] = i1;
          }
        }
      }
      __syncthreads();
    }
  }
  if (tid < MSEL) top[tid] = ki[tid];
}

// ---------------- K3: lexsort by (start,end,pos) asc, reversed ----------------
__global__ __launch_bounds__(256) void lexsort_kernel(
    const int* __restrict__ top, const int* __restrict__ sst,
    const int* __restrict__ sen, const float* __restrict__ scores,
    int* __restrict__ perm, float* __restrict__ sfin) {
  __shared__ int s_st[512], s_en[512], s_j[512];
  const int tid = threadIdx.x;
  for (int e = tid; e < 512; e += 256) {
    if (e < MSEL) { const int ti = top[e]; s_st[e] = sst[ti]; s_en[e] = sen[ti]; }
    else { s_st[e] = 0x7fffffff; s_en[e] = 0x7fffffff; }
    s_j[e] = e;
  }
  __syncthreads();
  for (int k = 2; k <= 512; k <<= 1) {
    for (int j = k >> 1; j > 0; j >>= 1) {
      for (int e = tid; e < 512; e += 256) {
        const int l = e ^ j;
        if (l > e) {
          const int a0 = s_st[e], a1 = s_en[e], a2 = s_j[e];
          const int b0 = s_st[l], b1 = s_en[l], b2 = s_j[l];
          const bool first = (a0 < b0) || (a0 == b0 && (a1 < b1 || (a1 == b1 && a2 < b2)));
          const bool up = ((e & k) == 0);
          if (up ? !first : first) {
            s_st[e] = b0; s_en[e] = b1; s_j[e] = b2;
            s_st[l] = a0; s_en[l] = a1; s_j[l] = a2;
          }
        }
      }
      __syncthreads();
    }
  }
  for (int i = tid; i < MSEL; i += 256) {
    const int src = s_j[MSEL - 1 - i];
    const int vi = top[src];
    perm[i] = vi;
    sfin[i] = scores[vi];
  }
}

// ---------------- K4: Ha = v@Wa, Hv = v@Wb; gather Vp (f32) + Vpb (bf16) ----------------
__global__ __launch_bounds__(256) void hab_kernel(
    const float* __restrict__ vectors, const float* __restrict__ Wp1,
    const int* __restrict__ perm, float* __restrict__ Ha, float* __restrict__ Hv,
    float* __restrict__ Vp, ushort* __restrict__ Vpb) {
  __shared__ float vrow[4 * DD];
  const int tid = threadIdx.x;
  const int base = blockIdx.x * 4;
  const int mat = blockIdx.y >> 1;       // 0 = Wa, 1 = Wb
  const int half = blockIdx.y & 1;       // col half
  for (int r = 0; r < 4; ++r) {
    const int pi = perm[base + r];
    for (int d = tid; d < DD; d += 256) {
      const float val = vectors[pi * DD + d];
      vrow[r * DD + d] = val;
      if (blockIdx.y == 0) {
        Vp[(size_t)(base + r) * DD + d] = val;
        Vpb[(size_t)(base + r) * DD + d] = (ushort)f2bf(val);
      }
    }
  }
  __syncthreads();
  float acc[4][2];
#pragma unroll
  for (int r = 0; r < 4; ++r) { acc[r][0] = 0.f; acc[r][1] = 0.f; }
  const float* W = Wp1 + (size_t)mat * DD * HH + half * 512;
#pragma unroll 2
  for (int d = 0; d < DD; d += 4) {
    float2 w0 = ((const float2*)(W + (size_t)(d + 0) * HH))[tid];
    float2 w1 = ((const float2*)(W + (size_t)(d + 1) * HH))[tid];
    float2 w2 = ((const float2*)(W + (size_t)(d + 2) * HH))[tid];
    float2 w3 = ((const float2*)(W + (size_t)(d + 3) * HH))[tid];
#pragma unroll
    for (int r = 0; r < 4; ++r) {
      const float4 a = *(const float4*)(vrow + r * DD + d);
      acc[r][0] += a.x * w0.x; acc[r][1] += a.x * w0.y;
      acc[r][0] += a.y * w1.x; acc[r][1] += a.y * w1.y;
      acc[r][0] += a.z * w2.x; acc[r][1] += a.z * w2.y;
      acc[r][0] += a.w * w3.x; acc[r][1] += a.w * w3.y;
    }
  }
  float* dst = mat ? Hv : Ha;
  for (int r = 0; r < 4; ++r) {
    const int row = base + r;
    if (mat == 0 && row >= MR) continue;
    ((float2*)(dst + (size_t)row * HH + half * 512))[tid] =
        make_float2(acc[r][0], acc[r][1]);
  }
}

// ---------------- K4b: Wt[n][k] = bf16(Wab[k][n]) (transpose + cast, once) ----------------
__global__ __launch_bounds__(256) void wt_kernel(
    const float* __restrict__ Wp1, ushort* __restrict__ Wt) {
  __shared__ float tile[64][65];
  const int kb = blockIdx.x;   // 12 tiles over K=768
  const int nb = blockIdx.y;   // 16 tiles over N=1024
  const float* Wab = Wp1 + 2 * DD * HH;
  for (int idx = threadIdx.x; idx < 64 * 64; idx += 256) {
    const int kk = idx >> 6, nn = idx & 63;
    tile[kk][nn] = Wab[(size_t)(kb * 64 + kk) * HH + nb * 64 + nn];
  }
  __syncthreads();
  for (int idx = threadIdx.x; idx < 64 * 64; idx += 256) {
    const int nn = idx >> 6, kk = idx & 63;
    Wt[(size_t)(nb * 64 + nn) * DD + kb * 64 + kk] = (ushort)f2bf(tile[kk][nn]);
  }
}

// ---------------- K5: pairwise einsum GEMM, 256x256 tile, 8 waves (m201 geometry) ----------------
// Block = (i, nb): 256 pair-rows (FULL antecedent range of anaphor i) x 256 h-cols.
// 8 waves 2Mx4N, wave tile 128x64 (acc 8x4). Per kt: issue B-DMA(kt+1) + A-src
// global loads(kt+1), 64 MFMA/wave on buf[cur], prodcvt+ds_write A(kt+1), one barrier.
// 4x the MFMA work per barrier vs the 128^2 tile; reads/MFMA 0.375 vs 0.5.
__global__ __launch_bounds__(512, 2) void pair_kernel(
    const float* __restrict__ Vp, const ushort* __restrict__ Vpb,
    const ushort* __restrict__ Wt,
    const float* __restrict__ bp1, const float* __restrict__ wp2,
    const float* __restrict__ Ha, const float* __restrict__ Hv,
    float* __restrict__ pp) {
  __shared__ __align__(16) ushort As[2][BM * BK];   // 2 x 32 KB
  __shared__ __align__(16) ushort Bs[2][BN * BK];   // 2 x 32 KB
  __shared__ float redp[BM][4];
  const int tid = threadIdx.x;
  const int i = blockIdx.x;           // 0..398
  const int nb = blockIdx.y;          // 0..3
  const int n0 = nb * BN;
  const int lane = tid & 63;
  const int wid = tid >> 6;           // 0..7
  const int wr = wid >> 2, wc = wid & 3;
  const int lhi = lane >> 4, llo = lane & 15;

  // ---- stage geometry: 4 chunks/thread; cs and swizzled slot constant ----
  const int cs = tid & 7;
  const int rbase = tid >> 3;                 // row mod 64 part
  const int csx = cs ^ (rbase & 7);           // same for all 4 chunks
  const ushort* vsrc[4];
  int rowA[4];
#pragma unroll
  for (int it = 0; it < 4; ++it) {
    rowA[it] = it * 64 + rbase;
    int j = i + 1 + rowA[it];
    if (j > MR) j = MR;
    vsrc[it] = Vpb + (size_t)j * DD + cs * 8;
  }
  const float* avp = Vp + (size_t)i * DD + cs * 8;   // L1-hot row i

  f32x4 acc[8][4];
#pragma unroll
  for (int a = 0; a < 8; ++a)
#pragma unroll
    for (int b = 0; b < 4; ++b) acc[a][b] = (f32x4){0.f, 0.f, 0.f, 0.f};

  // ---- prologue: DMA B(0); products A(0) ----
#pragma unroll
  for (int it = 0; it < 4; ++it) {
    gload_lds16(Wt + (size_t)(n0 + rowA[it]) * DD + csx * 8,
                (char*)Bs[0] + (it * 512 + tid) * 16);
  }
  {
    float av[8];
    *(float4*)(av) = *(const float4*)(avp);
    *(float4*)(av + 4) = *(const float4*)(avp + 4);
#pragma unroll
    for (int it = 0; it < 4; ++it) {
      const bf16x8 bv = *(const bf16x8*)(vsrc[it]);
      *(bf16x8*)((char*)As[0] + rowA[it] * 128 + (csx << 4)) = prodcvt(av, bv);
    }
  }
  __syncthreads();

  int cur = 0;
  for (int kt = 0; kt < NKT; ++kt) {
    const bool has_next = (kt + 1 < NKT);
    const int kgn = (kt + 1) * BK;
    bf16x8 bvn[4];
    float avn[8];
    if (has_next) {
      // (1) B prefetch: async global->LDS into Bs[cur^1]
      char* Bn = (char*)Bs[cur ^ 1];
#pragma unroll
      for (int it = 0; it < 4; ++it) {
        gload_lds16(Wt + (size_t)(n0 + rowA[it]) * DD + kgn + csx * 8,
                    Bn + (it * 512 + tid) * 16);
      }
      // (2) A source prefetch into registers
#pragma unroll
      for (int it = 0; it < 4; ++it) bvn[it] = *(const bf16x8*)(vsrc[it] + kgn);
      *(float4*)(avn) = *(const float4*)(avp + kgn);
      *(float4*)(avn + 4) = *(const float4*)(avp + kgn + 4);
    }
    // (3) MFMA on buf[cur]: 2 k-steps of 32; 8x4 fragment grid per wave
    const char* Ab = (const char*)As[cur];
    const char* Bb = (const char*)Bs[cur];
#pragma unroll
    for (int ks = 0; ks < 2; ++ks) {
      bf16x8 af[8], bfr[4];
#pragma unroll
      for (int mi = 0; mi < 8; ++mi) {
        const int row = wr * 128 + mi * 16 + llo;
        const int ch = (ks * 4 + lhi) ^ (row & 7);
        af[mi] = *(const bf16x8*)(Ab + row * 128 + (ch << 4));
      }
#pragma unroll
      for (int ni = 0; ni < 4; ++ni) {
        const int row = wc * 64 + ni * 16 + llo;
        const int ch = (ks * 4 + lhi) ^ (row & 7);
        bfr[ni] = *(const bf16x8*)(Bb + row * 128 + (ch << 4));
      }
#pragma unroll
      for (int mi = 0; mi < 8; ++mi)
#pragma unroll
        for (int ni = 0; ni < 4; ++ni)
          acc[mi][ni] = __builtin_amdgcn_mfma_f32_16x16x32_bf16(af[mi], bfr[ni], acc[mi][ni], 0, 0, 0);
    }
    // (4) A products for kt+1 (sources have had the MFMA phase to land)
    if (has_next) {
      char* An = (char*)As[cur ^ 1];
#pragma unroll
      for (int it = 0; it < 4; ++it)
        *(bf16x8*)(An + rowA[it] * 128 + (csx << 4)) = prodcvt(avn, bvn[it]);
    }
    // (5) one barrier per kt
    __syncthreads();
    cur ^= 1;
  }

  // ---- epilogue: relu(acc + Ha_i + Hv_j + bp1) . wp2 over this wave's 64 cols ----
  float hb4[4], wpv[4];
  int cg[4];
#pragma unroll
  for (int ni = 0; ni < 4; ++ni) {
    const int col = n0 + wc * 64 + ni * 16 + llo;
    cg[ni] = col;
    hb4[ni] = Ha[(size_t)i * HH + col] + bp1[col];
    wpv[ni] = wp2[col];
  }
#pragma unroll
  for (int mi = 0; mi < 8; ++mi) {
#pragma unroll
    for (int r = 0; r < 4; ++r) {
      const int rowl = wr * 128 + mi * 16 + lhi * 4 + r;
      int j = i + 1 + rowl;
      if (j > MR) j = MR;
      float part = 0.f;
#pragma unroll
      for (int ni = 0; ni < 4; ++ni) {
        const float pre = acc[mi][ni][r] + hb4[ni] + Hv[(size_t)j * HH + cg[ni]];
        part += fmaxf(pre, 0.f) * wpv[ni];
      }
      part += __shfl_xor(part, 1, 64);
      part += __shfl_xor(part, 2, 64);
      part += __shfl_xor(part, 4, 64);
      part += __shfl_xor(part, 8, 64);
      if (llo == 0) redp[rowl][wc] = part;   // per-wave column-quarter partial
    }
  }
  __syncthreads();
  if (tid < BM)
    pp[(size_t)nb * NPAIR + (size_t)i * PPAD + tid] =
        redp[tid][0] + redp[tid][1] + redp[tid][2] + redp[tid][3];
}

// ---------------- K6: sum partials + bias + scores, mask, softmax over 251 ----------------
__global__ __launch_bounds__(256) void softmax_kernel(
    const float* __restrict__ pp, const float* __restrict__ sfin,
    const float* __restrict__ bp2, float* __restrict__ out) {
  __shared__ float red[4];
  const int i = blockIdx.x, tid = threadIdx.x;
  float v;
  if (tid < KNUM) {
    const int jidx = i + 1 + tid;
    const bool valid = jidx < MSEL;
    const int jc = valid ? jidx : MR;
    float s = 0.f;
#pragma unroll
    for (int b = 0; b < NNB; ++b) s += pp[(size_t)b * NPAIR + i * PPAD + tid];
    v = valid ? (s + bp2[0] + sfin[jc] + sfin[i]) : -INFINITY;
  } else if (tid == KNUM) v = 0.f;
  else v = -INFINITY;
  float mx = waveMax(v);
  if ((tid & 63) == 0) red[tid >> 6] = mx;
  __syncthreads();
  const float m = fmaxf(fmaxf(red[0], red[1]), fmaxf(red[2], red[3]));
  __syncthreads();
  const float e = (tid <= KNUM) ? expf(v - m) : 0.f;
  float s = waveSum(e);
  if ((tid & 63) == 0) red[tid >> 6] = s;
  __syncthreads();
  const float tot = red[0] + red[1] + red[2] + red[3];
  if (tid <= KNUM) out[i * OUTW + tid] = e / tot;
}

extern "C" void kernel_launch(void* const* d_in, const int* in_sizes, int n_in,
                              void* d_out, int out_size, void* d_ws, size_t ws_size,
                              hipStream_t stream) {
  const float* vectors = (const float*)d_in[0];
  const float* Wm1 = (const float*)d_in[1];
  const float* bm1 = (const float*)d_in[2];
  const float* wm2 = (const float*)d_in[3];
  const float* bm2 = (const float*)d_in[4];
  const float* Wp1 = (const float*)d_in[5];
  const float* bp1 = (const float*)d_in[6];
  const float* wp2 = (const float*)d_in[7];
  const float* bp2 = (const float*)d_in[8];
  const int* sst = (const int*)d_in[9];
  const int* sen = (const int*)d_in[10];
  float* out = (float*)d_out;
  char* ws = (char*)d_ws;

  float* scores = (float*)(ws);                          // 2000 f32
  int*   top    = (int*)(ws + 8192);                     // 400 i32
  int*   perm   = (int*)(ws + 10240);                    // 400 i32
  float* sfin   = (float*)(ws + 12288);                  // 400 f32
  float* Ha     = (float*)(ws + 16384);                  // 400*1024 f32
  float* Hv     = (float*)(ws + 16384 + 1638400);        // 400*1024 f32
  float* Vp     = (float*)(ws + 3293184);                // 400*768 f32
  ushort* Wt    = (ushort*)(ws + 4521984);               // 1024*768 bf16
  ushort* Vpb   = (ushort*)(ws + 6094848);               // 400*768 bf16
  float* pp     = (float*)(ws + 6709248);                // 4 * 102144 f32 partials

  scores_kernel<<<NVEC / 4, 512, 0, stream>>>(vectors, Wm1, bm1, wm2, bm2, scores);
  topsort_kernel<<<1, 1024, 0, stream>>>(scores, top);
  lexsort_kernel<<<1, 256, 0, stream>>>(top, sst, sen, scores, perm, sfin);
  wt_kernel<<<dim3(12, 16), 256, 0, stream>>>(Wp1, Wt);
  hab_kernel<<<dim3(MSEL / 4, 4), 256, 0, stream>>>(vectors, Wp1, perm, Ha, Hv, Vp, Vpb);
  pair_kernel<<<dim3(MR, NNB), 512, 0, stream>>>(Vp, Vpb, Wt, bp1, wp2, Ha, Hv, pp);
  softmax_kernel<<<MR, 256, 0, stream>>>(pp, sfin, bp2, out);
}